// Round 2
// baseline (624.371 us; speedup 1.0000x reference)
//
#include <hip/hip_runtime.h>
#include <math.h>

#define B_    512
#define V_    6890
#define J_    24
#define NB_   10
#define K_    207     // 9*(J-1)
#define KPAD  224     // 7 chunks of 32
#define NCOL  20670   // V*3

typedef __attribute__((ext_vector_type(8))) __bf16 bf16x8;
typedef __attribute__((ext_vector_type(4))) float  f32x4;

__constant__ int c_par[24] = {-1,0,0,0,1,2,3,4,5,6,7,8,9,9,9,12,13,14,16,17,18,19,20,21};
__constant__ int c_lev[24] = { 0,1,1,1,2,2,2,3,3,3,4,4,4,4,4, 5, 5, 5, 6, 6, 7, 7, 8, 8};

__device__ __forceinline__ unsigned short f2bf(float x) {
    union { float f; unsigned u; } v; v.f = x;
    unsigned r = (v.u + 0x7FFFu + ((v.u >> 16) & 1u)) >> 16;
    return (unsigned short)r;
}

// ---------------------------------------------------------------------------
// K1: JT[j][k] = sum_v Jreg[j][v]*vt[v][k];  JS[j][k][l] = sum_v Jreg[j][v]*sd[v][k][l]
// ---------------------------------------------------------------------------
__global__ __launch_bounds__(256) void k_jreg(const float* __restrict__ Jreg,
                                              const float* __restrict__ vt,
                                              const float* __restrict__ sd,
                                              float* __restrict__ JS,
                                              float* __restrict__ JT)
{
    const int j = blockIdx.x / 3, k = blockIdx.x % 3;
    const int tid = threadIdx.x;
    float acc[11];
#pragma unroll
    for (int i = 0; i < 11; ++i) acc[i] = 0.f;

    for (int v = tid; v < V_; v += 256) {
        const float r = Jreg[j * V_ + v];
        acc[0] = fmaf(r, vt[v * 3 + k], acc[0]);
        const float* s = &sd[(v * 3 + k) * NB_];
#pragma unroll
        for (int l = 0; l < NB_; ++l) acc[1 + l] = fmaf(r, s[l], acc[1 + l]);
    }

    __shared__ float red[4][11];
    const int lane = tid & 63, w = tid >> 6;
#pragma unroll
    for (int i = 0; i < 11; ++i) {
        float a = acc[i];
        for (int off = 32; off; off >>= 1) a += __shfl_xor(a, off, 64);
        acc[i] = a;
    }
    if (lane == 0) {
#pragma unroll
        for (int i = 0; i < 11; ++i) red[w][i] = acc[i];
    }
    __syncthreads();
    if (tid == 0) {
        for (int i = 0; i < 11; ++i) {
            const float s = red[0][i] + red[1][i] + red[2][i] + red[3][i];
            if (i == 0) JT[j * 3 + k] = s;
            else        JS[(j * 3 + k) * NB_ + (i - 1)] = s;
        }
    }
}

// ---------------------------------------------------------------------------
// K2: per-batch joint pipeline. grid = 512, block = 64.
// pose_feature written as bf16 [B][KPAD], zero padded k=207..223.
// ---------------------------------------------------------------------------
__global__ __launch_bounds__(64) void k_pose(const float* __restrict__ betas,
                                             const float* __restrict__ body_pose,
                                             const float* __restrict__ global_orient,
                                             const float* __restrict__ transl,
                                             const float* __restrict__ JS,
                                             const float* __restrict__ JT,
                                             float* __restrict__ Aout,
                                             unsigned short* __restrict__ pfout,
                                             float* __restrict__ joints_out)
{
    const int b = blockIdx.x;
    const int j = threadIdx.x;

    __shared__ float sR[24][9];
    __shared__ float sJ[24][3];
    __shared__ float sTl[24][12];
    __shared__ float sTg[24][12];

    if (j < 24) {
        float rx, ry, rz;
        if (j == 0) {
            rx = global_orient[b * 3 + 0];
            ry = global_orient[b * 3 + 1];
            rz = global_orient[b * 3 + 2];
        } else {
            const float* p = &body_pose[b * 69 + (j - 1) * 3];
            rx = p[0]; ry = p[1]; rz = p[2];
        }
        const float ax = rx + 1e-8f, ay = ry + 1e-8f, az = rz + 1e-8f;
        const float angle = sqrtf(ax * ax + ay * ay + az * az);
        const float inv = 1.f / angle;
        const float x = rx * inv, y = ry * inv, z = rz * inv;
        const float s = sinf(angle), c = cosf(angle), t = 1.f - c;

        float R[9];
        R[0] = 1.f - t * (y * y + z * z);
        R[1] = -s * z + t * x * y;
        R[2] =  s * y + t * x * z;
        R[3] =  s * z + t * x * y;
        R[4] = 1.f - t * (x * x + z * z);
        R[5] = -s * x + t * y * z;
        R[6] = -s * y + t * x * z;
        R[7] =  s * x + t * y * z;
        R[8] = 1.f - t * (x * x + y * y);

#pragma unroll
        for (int e = 0; e < 9; ++e) sR[j][e] = R[e];

        if (j >= 1) {
#pragma unroll
            for (int e = 0; e < 9; ++e) {
                const float id = (e == 0 || e == 4 || e == 8) ? 1.f : 0.f;
                pfout[b * KPAD + (j - 1) * 9 + e] = f2bf(R[e] - id);
            }
        }
#pragma unroll
        for (int k = 0; k < 3; ++k) {
            float jr = JT[j * 3 + k];
#pragma unroll
            for (int l = 0; l < NB_; ++l)
                jr = fmaf(betas[b * NB_ + l], JS[(j * 3 + k) * NB_ + l], jr);
            sJ[j][k] = jr;
        }
    }
    if (j >= 24 && j < 24 + (KPAD - K_)) pfout[b * KPAD + K_ + (j - 24)] = 0;
    __syncthreads();

    if (j < 24) {
        const int p = c_par[j];
        float t0 = sJ[j][0], t1 = sJ[j][1], t2 = sJ[j][2];
        if (j > 0) { t0 -= sJ[p][0]; t1 -= sJ[p][1]; t2 -= sJ[p][2]; }
        sTl[j][0] = sR[j][0]; sTl[j][1] = sR[j][1]; sTl[j][2]  = sR[j][2]; sTl[j][3]  = t0;
        sTl[j][4] = sR[j][3]; sTl[j][5] = sR[j][4]; sTl[j][6]  = sR[j][5]; sTl[j][7]  = t1;
        sTl[j][8] = sR[j][6]; sTl[j][9] = sR[j][7]; sTl[j][10] = sR[j][8]; sTl[j][11] = t2;
    }
    __syncthreads();

    if (j == 0) {
#pragma unroll
        for (int e = 0; e < 12; ++e) sTg[0][e] = sTl[0][e];
    }
    __syncthreads();

    for (int lev = 1; lev <= 8; ++lev) {
        if (j < 24 && c_lev[j] == lev) {
            const int p = c_par[j];
            float o[12];
#pragma unroll
            for (int r = 0; r < 3; ++r) {
#pragma unroll
                for (int c = 0; c < 4; ++c) {
                    float v = (c == 3) ? sTg[p][r * 4 + 3] : 0.f;
#pragma unroll
                    for (int m = 0; m < 3; ++m)
                        v = fmaf(sTg[p][r * 4 + m], sTl[j][m * 4 + c], v);
                    o[r * 4 + c] = v;
                }
            }
#pragma unroll
            for (int e = 0; e < 12; ++e) sTg[j][e] = o[e];
        }
        __syncthreads();
    }

    if (j < 24) {
        float corr[3];
#pragma unroll
        for (int r = 0; r < 3; ++r)
            corr[r] = sTg[j][r * 4 + 0] * sJ[j][0] + sTg[j][r * 4 + 1] * sJ[j][1]
                    + sTg[j][r * 4 + 2] * sJ[j][2];
        float* Ab = &Aout[(b * 24 + j) * 12];
#pragma unroll
        for (int r = 0; r < 3; ++r) {
            Ab[r * 4 + 0] = sTg[j][r * 4 + 0];
            Ab[r * 4 + 1] = sTg[j][r * 4 + 1];
            Ab[r * 4 + 2] = sTg[j][r * 4 + 2];
            Ab[r * 4 + 3] = sTg[j][r * 4 + 3] - corr[r];
        }
#pragma unroll
        for (int k = 0; k < 3; ++k)
            joints_out[(b * 24 + j) * 3 + k] = sTg[j][k * 4 + 3] + transl[b * 3 + k];
    }
}

// ---------------------------------------------------------------------------
// K3: MFMA pose-blend GEMM + scalar-pipe LBS epilogue.
// grid = 864 (XCD-chunked remap: 108 vtiles x 8 btiles), block = 256 (4 waves).
// Tile: 64 batches x 64 verts (192 cols). Wave w owns batches w*16..+16.
// LDS union: GEMM staging (pf[64][40] + pd[192][40] bf16 = 20.5 KB)
//            vs disp buffer (4 waves x 8 rows x 194 f32 = 24.8 KB).
// ---------------------------------------------------------------------------
__global__ __launch_bounds__(256, 3) void k_verts(
    const float* __restrict__ betas,
    const float* __restrict__ v_template,
    const float* __restrict__ shapedirs,
    const float* __restrict__ posedirs,
    const float* __restrict__ lbs_weights,
    const float* __restrict__ transl,
    const unsigned short* __restrict__ pf,   // [B][224] bf16
    const float* __restrict__ A,             // [B][24][12]
    float* __restrict__ out)                 // [B][V][3]
{
    __shared__ __align__(16) char smem[25088];
    unsigned short* s_pf = (unsigned short*)smem;            // [64][40]
    unsigned short* s_pd = (unsigned short*)(smem + 5120);   // [192][40]
    float*          s_disp = (float*)smem;                   // [4][8][194] (reuse)

    const int tid = threadIdx.x;
    const int l   = tid & 63;
    const int wv  = tid >> 6;
    const int m   = l & 15;
    const int g   = l >> 4;

    // XCD-chunked remap: XCD x gets a contiguous vtile range with all btiles,
    // so each posedirs panel is fetched into one XCD's L2 once.
    const int lraw  = blockIdx.x;                 // 864 = 108*8
    const int gl    = (lraw & 7) * 108 + (lraw >> 3);
    const int vtile = gl >> 3;                    // 0..107
    const int btile = gl & 7;                     // 0..7
    const int vbase = vtile * 64;
    const int bbase = btile * 64;
    const int vb3   = vtile * 192;
    const bool colsafe = (vb3 + 192 <= NCOL);

    f32x4 acc[12];
#pragma unroll
    for (int i = 0; i < 12; ++i) acc[i] = (f32x4){0.f, 0.f, 0.f, 0.f};

    // ---- GEMM: disp[b][c] = sum_k pf[b][k] * posedirs[k][c], 7 K-chunks ----
    for (int kc = 0; kc < KPAD; kc += 32) {
        __syncthreads();
        // stage pf tile [64][32] bf16 (already bf16 in ws)
        {
            const int row = tid >> 2, kq = tid & 3;
            int4 vld = *(const int4*)&pf[(bbase + row) * KPAD + kc + kq * 8];
            *(int4*)&s_pf[row * 40 + kq * 8] = vld;
        }
        // stage pd tile transposed -> [col 192][k 40] bf16, 24 scalars/thread
        {
            int c = tid % 192;
            int kk = tid / 192;
#pragma unroll
            for (int s = 0; s < 24; ++s) {
                const int gk = kc + kk, gc = vb3 + c;
                float x = 0.f;
                if (gk < K_ && (colsafe || gc < NCOL))
                    x = posedirs[gk * NCOL + gc];
                s_pd[c * 40 + kk] = f2bf(x);
                c += 64; ++kk;
                if (c >= 192) { c -= 192; ++kk; }
            }
        }
        __syncthreads();
        // A-frag: row = w*16 + (l&15), k = 8*(l>>4)+e ; B-frag: col, same k
        bf16x8 af = *(const bf16x8*)&s_pf[(wv * 16 + m) * 40 + g * 8];
#pragma unroll
        for (int nt = 0; nt < 12; ++nt) {
            bf16x8 bfr = *(const bf16x8*)&s_pd[(nt * 16 + m) * 40 + g * 8];
            acc[nt] = __builtin_amdgcn_mfma_f32_16x16x32_bf16(af, bfr, acc[nt], 0, 0, 0);
        }
    }

    // ---- epilogue preloads (per-lane vertex data, hide latency pre-barrier) ----
    const int v  = vbase + l;
    const int vc = v < V_ ? v : V_ - 1;
    float w24[24];
#pragma unroll
    for (int q = 0; q < 6; ++q) {
        float4 t = *(const float4*)&lbs_weights[vc * 24 + q * 4];
        w24[q * 4 + 0] = t.x; w24[q * 4 + 1] = t.y;
        w24[q * 4 + 2] = t.z; w24[q * 4 + 3] = t.w;
    }
    float sd[30];
#pragma unroll
    for (int i = 0; i < 30; ++i) sd[i] = shapedirs[vc * 30 + i];
    const float vt0 = v_template[vc * 3 + 0];
    const float vt1 = v_template[vc * 3 + 1];
    const float vt2 = v_template[vc * 3 + 2];

    const int wvs = __builtin_amdgcn_readfirstlane(wv);

    __syncthreads();   // all MFMA LDS reads done before disp overwrites staging

    // ---- two half-passes over this wave's 16 batches (8 rows each) ----
#pragma unroll
    for (int h = 0; h < 2; ++h) {
        // dump acc rows [8h, 8h+8): lanes with l>>4 in {2h, 2h+1}
        if ((g >> 1) == h) {
            const int rb = (g & 1) * 4;
#pragma unroll
            for (int nt = 0; nt < 12; ++nt) {
#pragma unroll
                for (int r = 0; r < 4; ++r)
                    s_disp[wv * 1552 + (rb + r) * 194 + nt * 16 + m] = acc[nt][r];
            }
        }
        __syncthreads();

#pragma unroll
        for (int bi = 0; bi < 8; ++bi) {
            const int b = bbase + wvs * 16 + h * 8 + bi;     // wave-uniform
            const float* __restrict__ bb = &betas[b * NB_];  // -> s_load
            const float* __restrict__ Ab = &A[b * 288];      // -> s_load

            // v_shaped = template + betas . shapedirs  (SGPR x VGPR FMAs)
            float vpx = vt0, vpy = vt1, vpz = vt2;
#pragma unroll
            for (int q = 0; q < NB_; ++q) {
                const float bq = bb[q];
                vpx = fmaf(bq, sd[q],      vpx);
                vpy = fmaf(bq, sd[10 + q], vpy);
                vpz = fmaf(bq, sd[20 + q], vpz);
            }
            // + pose displacement from LDS
            vpx += s_disp[wv * 1552 + bi * 194 + 3 * l + 0];
            vpy += s_disp[wv * 1552 + bi * 194 + 3 * l + 1];
            vpz += s_disp[wv * 1552 + bi * 194 + 3 * l + 2];

            // T = sum_j w[v,j] * A[b,j]  (VGPR x SGPR FMAs, 1 SGPR/instr)
            float T[12];
#pragma unroll
            for (int e = 0; e < 12; ++e) T[e] = 0.f;
#pragma unroll
            for (int j = 0; j < 24; ++j) {
                const float wj = w24[j];
#pragma unroll
                for (int e = 0; e < 12; ++e) T[e] = fmaf(wj, Ab[j * 12 + e], T[e]);
            }

            const float ox = fmaf(T[0], vpx, fmaf(T[1], vpy, fmaf(T[2],  vpz, T[3])))  + transl[b * 3 + 0];
            const float oy = fmaf(T[4], vpx, fmaf(T[5], vpy, fmaf(T[6],  vpz, T[7])))  + transl[b * 3 + 1];
            const float oz = fmaf(T[8], vpx, fmaf(T[9], vpy, fmaf(T[10], vpz, T[11]))) + transl[b * 3 + 2];

            if (v < V_) {
                float* o = &out[((size_t)b * V_ + v) * 3];
                o[0] = ox; o[1] = oy; o[2] = oz;
            }
        }
        __syncthreads();
    }
}

// ---------------------------------------------------------------------------
extern "C" void kernel_launch(void* const* d_in, const int* in_sizes, int n_in,
                              void* d_out, int out_size, void* d_ws, size_t ws_size,
                              hipStream_t stream)
{
    const float* betas         = (const float*)d_in[0];
    const float* body_pose     = (const float*)d_in[1];
    const float* global_orient = (const float*)d_in[2];
    const float* transl        = (const float*)d_in[3];
    const float* v_template    = (const float*)d_in[4];
    const float* shapedirs     = (const float*)d_in[5];
    const float* posedirs      = (const float*)d_in[6];
    const float* J_regressor   = (const float*)d_in[7];
    const float* lbs_weights   = (const float*)d_in[8];

    float* out = (float*)d_out;
    float* ws  = (float*)d_ws;

    // ws layout (floats): JS[720] | JT[72] | A[512*24*12] | pf bf16 [512*224]
    float* JS  = ws;
    float* JT  = ws + 720;
    float* Aw  = ws + 792;
    unsigned short* pfw = (unsigned short*)(ws + 792 + (size_t)B_ * 24 * 12);

    float* joints = out + (size_t)B_ * V_ * 3;

    k_jreg <<<72, 256, 0, stream>>>(J_regressor, v_template, shapedirs, JS, JT);
    k_pose <<<B_, 64, 0, stream>>>(betas, body_pose, global_orient, transl,
                                   JS, JT, Aw, pfw, joints);
    k_verts<<<864, 256, 0, stream>>>(betas, v_template, shapedirs, posedirs,
                                     lbs_weights, transl, pfw, Aw, out);
}

// Round 3
// 171.044 us; speedup vs baseline: 3.6504x; 3.6504x over previous
//
#include <hip/hip_runtime.h>
#include <math.h>

#define B_    512
#define V_    6890
#define J_    24
#define NB_   10
#define K_    207     // 9*(J-1)
#define KPAD  224     // 7 chunks of 32
#define NCOL  20670   // V*3
#define CPAD  20736   // 108 vtiles * 192 cols

typedef __attribute__((ext_vector_type(8))) __bf16 bf16x8;
typedef __attribute__((ext_vector_type(4))) float  f32x4;

__constant__ int c_par[24] = {-1,0,0,0,1,2,3,4,5,6,7,8,9,9,9,12,13,14,16,17,18,19,20,21};
__constant__ int c_lev[24] = { 0,1,1,1,2,2,2,3,3,3,4,4,4,4,4, 5, 5, 5, 6, 6, 7, 7, 8, 8};

__device__ __forceinline__ unsigned short f2bf(float x) {
    union { float f; unsigned u; } v; v.f = x;
    unsigned r = (v.u + 0x7FFFu + ((v.u >> 16) & 1u)) >> 16;
    return (unsigned short)r;
}

// ---------------------------------------------------------------------------
// K0: one-time posedirs f32 [207][20670] -> bf16 transposed [CPAD][KPAD].
// grid (324, 7) x 256: 64 cols x 4 kq per block; reads coalesced along cols.
// ---------------------------------------------------------------------------
__global__ __launch_bounds__(256) void k_cvt(const float* __restrict__ pd,
                                             unsigned short* __restrict__ pdT)
{
    const int c  = blockIdx.x * 64 + (threadIdx.x & 63);
    const int kq = blockIdx.y * 4 + (threadIdx.x >> 6);
    unsigned short u[8];
#pragma unroll
    for (int e = 0; e < 8; ++e) {
        const int k = kq * 8 + e;
        float x = 0.f;
        if (k < K_ && c < NCOL) x = pd[(size_t)k * NCOL + c];
        u[e] = f2bf(x);
    }
    *reinterpret_cast<uint4*>(&pdT[(size_t)c * KPAD + kq * 8]) =
        *reinterpret_cast<const uint4*>(u);
}

// ---------------------------------------------------------------------------
// K1: JT[j][k] = sum_v Jreg[j][v]*vt[v][k];  JS[j][k][l] = sum_v Jreg[j][v]*sd[v][k][l]
// ---------------------------------------------------------------------------
__global__ __launch_bounds__(256) void k_jreg(const float* __restrict__ Jreg,
                                              const float* __restrict__ vt,
                                              const float* __restrict__ sd,
                                              float* __restrict__ JS,
                                              float* __restrict__ JT)
{
    const int j = blockIdx.x / 3, k = blockIdx.x % 3;
    const int tid = threadIdx.x;
    float acc[11];
#pragma unroll
    for (int i = 0; i < 11; ++i) acc[i] = 0.f;

    for (int v = tid; v < V_; v += 256) {
        const float r = Jreg[j * V_ + v];
        acc[0] = fmaf(r, vt[v * 3 + k], acc[0]);
        const float* s = &sd[(v * 3 + k) * NB_];
#pragma unroll
        for (int l = 0; l < NB_; ++l) acc[1 + l] = fmaf(r, s[l], acc[1 + l]);
    }

    __shared__ float red[4][11];
    const int lane = tid & 63, w = tid >> 6;
#pragma unroll
    for (int i = 0; i < 11; ++i) {
        float a = acc[i];
        for (int off = 32; off; off >>= 1) a += __shfl_xor(a, off, 64);
        acc[i] = a;
    }
    if (lane == 0) {
#pragma unroll
        for (int i = 0; i < 11; ++i) red[w][i] = acc[i];
    }
    __syncthreads();
    if (tid == 0) {
        for (int i = 0; i < 11; ++i) {
            const float s = red[0][i] + red[1][i] + red[2][i] + red[3][i];
            if (i == 0) JT[j * 3 + k] = s;
            else        JS[(j * 3 + k) * NB_ + (i - 1)] = s;
        }
    }
}

// ---------------------------------------------------------------------------
// K2: per-batch joint pipeline. grid = 512, block = 64.
// ---------------------------------------------------------------------------
__global__ __launch_bounds__(64) void k_pose(const float* __restrict__ betas,
                                             const float* __restrict__ body_pose,
                                             const float* __restrict__ global_orient,
                                             const float* __restrict__ transl,
                                             const float* __restrict__ JS,
                                             const float* __restrict__ JT,
                                             float* __restrict__ Aout,
                                             unsigned short* __restrict__ pfout,
                                             float* __restrict__ joints_out)
{
    const int b = blockIdx.x;
    const int j = threadIdx.x;

    __shared__ float sR[24][9];
    __shared__ float sJ[24][3];
    __shared__ float sTl[24][12];
    __shared__ float sTg[24][12];

    if (j < 24) {
        float rx, ry, rz;
        if (j == 0) {
            rx = global_orient[b * 3 + 0];
            ry = global_orient[b * 3 + 1];
            rz = global_orient[b * 3 + 2];
        } else {
            const float* p = &body_pose[b * 69 + (j - 1) * 3];
            rx = p[0]; ry = p[1]; rz = p[2];
        }
        const float ax = rx + 1e-8f, ay = ry + 1e-8f, az = rz + 1e-8f;
        const float angle = sqrtf(ax * ax + ay * ay + az * az);
        const float inv = 1.f / angle;
        const float x = rx * inv, y = ry * inv, z = rz * inv;
        const float s = sinf(angle), c = cosf(angle), t = 1.f - c;

        float R[9];
        R[0] = 1.f - t * (y * y + z * z);
        R[1] = -s * z + t * x * y;
        R[2] =  s * y + t * x * z;
        R[3] =  s * z + t * x * y;
        R[4] = 1.f - t * (x * x + z * z);
        R[5] = -s * x + t * y * z;
        R[6] = -s * y + t * x * z;
        R[7] =  s * x + t * y * z;
        R[8] = 1.f - t * (x * x + y * y);

#pragma unroll
        for (int e = 0; e < 9; ++e) sR[j][e] = R[e];

        if (j >= 1) {
#pragma unroll
            for (int e = 0; e < 9; ++e) {
                const float id = (e == 0 || e == 4 || e == 8) ? 1.f : 0.f;
                pfout[b * KPAD + (j - 1) * 9 + e] = f2bf(R[e] - id);
            }
        }
#pragma unroll
        for (int k = 0; k < 3; ++k) {
            float jr = JT[j * 3 + k];
#pragma unroll
            for (int l = 0; l < NB_; ++l)
                jr = fmaf(betas[b * NB_ + l], JS[(j * 3 + k) * NB_ + l], jr);
            sJ[j][k] = jr;
        }
    }
    if (j >= 24 && j < 24 + (KPAD - K_)) pfout[b * KPAD + K_ + (j - 24)] = 0;
    __syncthreads();

    if (j < 24) {
        const int p = c_par[j];
        float t0 = sJ[j][0], t1 = sJ[j][1], t2 = sJ[j][2];
        if (j > 0) { t0 -= sJ[p][0]; t1 -= sJ[p][1]; t2 -= sJ[p][2]; }
        sTl[j][0] = sR[j][0]; sTl[j][1] = sR[j][1]; sTl[j][2]  = sR[j][2]; sTl[j][3]  = t0;
        sTl[j][4] = sR[j][3]; sTl[j][5] = sR[j][4]; sTl[j][6]  = sR[j][5]; sTl[j][7]  = t1;
        sTl[j][8] = sR[j][6]; sTl[j][9] = sR[j][7]; sTl[j][10] = sR[j][8]; sTl[j][11] = t2;
    }
    __syncthreads();

    if (j == 0) {
#pragma unroll
        for (int e = 0; e < 12; ++e) sTg[0][e] = sTl[0][e];
    }
    __syncthreads();

    for (int lev = 1; lev <= 8; ++lev) {
        if (j < 24 && c_lev[j] == lev) {
            const int p = c_par[j];
            float o[12];
#pragma unroll
            for (int r = 0; r < 3; ++r) {
#pragma unroll
                for (int c = 0; c < 4; ++c) {
                    float v = (c == 3) ? sTg[p][r * 4 + 3] : 0.f;
#pragma unroll
                    for (int m = 0; m < 3; ++m)
                        v = fmaf(sTg[p][r * 4 + m], sTl[j][m * 4 + c], v);
                    o[r * 4 + c] = v;
                }
            }
#pragma unroll
            for (int e = 0; e < 12; ++e) sTg[j][e] = o[e];
        }
        __syncthreads();
    }

    if (j < 24) {
        float corr[3];
#pragma unroll
        for (int r = 0; r < 3; ++r)
            corr[r] = sTg[j][r * 4 + 0] * sJ[j][0] + sTg[j][r * 4 + 1] * sJ[j][1]
                    + sTg[j][r * 4 + 2] * sJ[j][2];
        float* Ab = &Aout[(b * 24 + j) * 12];
#pragma unroll
        for (int r = 0; r < 3; ++r) {
            Ab[r * 4 + 0] = sTg[j][r * 4 + 0];
            Ab[r * 4 + 1] = sTg[j][r * 4 + 1];
            Ab[r * 4 + 2] = sTg[j][r * 4 + 2];
            Ab[r * 4 + 3] = sTg[j][r * 4 + 3] - corr[r];
        }
#pragma unroll
        for (int k = 0; k < 3; ++k)
            joints_out[(b * 24 + j) * 3 + k] = sTg[j][k * 4 + 3] + transl[b * 3 + k];
    }
}

// ---------------------------------------------------------------------------
// K3: MFMA pose-blend GEMM (frags straight from L2, NO LDS staging, NO barriers)
//     + scalar-pipe LBS epilogue. grid = 864 (XCD-chunked), block = 256.
//     LDS: per-wave acc transpose buffer only, 4 x 16 x 194 f32 = 49.7 KB.
// ---------------------------------------------------------------------------
template<bool PRE>
__global__ __launch_bounds__(256, 3) void k_verts(
    const float* __restrict__ betas,
    const float* __restrict__ v_template,
    const float* __restrict__ shapedirs,
    const float* __restrict__ posedirs,          // f32, fallback only
    const unsigned short* __restrict__ pdT,      // bf16 [CPAD][KPAD], main path
    const float* __restrict__ lbs_weights,
    const float* __restrict__ transl,
    const unsigned short* __restrict__ pf,       // bf16 [B][KPAD]
    const float* __restrict__ A,                 // f32 [B][24][12]
    float* __restrict__ out)                     // [B][V][3] (+joints elsewhere)
{
    __shared__ float s_disp[4 * 16 * 194];       // per-wave private regions

    const int tid = threadIdx.x;
    const int l   = tid & 63;
    const int wv  = tid >> 6;
    const int m   = l & 15;
    const int g   = l >> 4;

    // XCD-chunked remap: each XCD owns a contiguous vtile range (all btiles).
    const int lraw  = blockIdx.x;                 // 864 = 108*8, %8==0 -> bijective
    const int gl    = (lraw & 7) * 108 + (lraw >> 3);
    const int vtile = gl >> 3;                    // 0..107
    const int btile = gl & 7;                     // 0..7
    const int vbase = vtile * 64;
    const int bbase = btile * 64;
    const int vb3   = vtile * 192;

    f32x4 acc[12];
#pragma unroll
    for (int i = 0; i < 12; ++i) acc[i] = (f32x4){0.f, 0.f, 0.f, 0.f};

    // ---- GEMM: 7 K-chunks, frags read per-lane from L2 (line-efficient) ----
#pragma unroll 1
    for (int kc = 0; kc < KPAD; kc += 32) {
        const bf16x8 af = *reinterpret_cast<const bf16x8*>(
            &pf[(size_t)(bbase + wv * 16 + m) * KPAD + kc + g * 8]);
        if (PRE) {
#pragma unroll
            for (int nt = 0; nt < 12; ++nt) {
                const bf16x8 bfr = *reinterpret_cast<const bf16x8*>(
                    &pdT[(size_t)(vb3 + nt * 16 + m) * KPAD + kc + g * 8]);
                acc[nt] = __builtin_amdgcn_mfma_f32_16x16x32_bf16(af, bfr, acc[nt], 0, 0, 0);
            }
        } else {
#pragma unroll
            for (int nt = 0; nt < 12; ++nt) {
                unsigned short u[8];
                const int ccol = vb3 + nt * 16 + m;
#pragma unroll
                for (int e = 0; e < 8; ++e) {
                    const int k = kc + g * 8 + e;
                    float x = (k < K_ && ccol < NCOL)
                              ? posedirs[(size_t)k * NCOL + ccol] : 0.f;
                    u[e] = f2bf(x);
                }
                const bf16x8 bfr = *reinterpret_cast<const bf16x8*>(u);
                acc[nt] = __builtin_amdgcn_mfma_f32_16x16x32_bf16(af, bfr, acc[nt], 0, 0, 0);
            }
        }
    }

    // ---- per-lane vertex preloads (issue while MFMAs drain) ----
    const int v  = vbase + l;
    const int vc = v < V_ ? v : V_ - 1;
    float w24[24];
#pragma unroll
    for (int q = 0; q < 6; ++q) {
        float4 t = *reinterpret_cast<const float4*>(&lbs_weights[vc * 24 + q * 4]);
        w24[q * 4 + 0] = t.x; w24[q * 4 + 1] = t.y;
        w24[q * 4 + 2] = t.z; w24[q * 4 + 3] = t.w;
    }
    float sd[30];
#pragma unroll
    for (int i = 0; i < 30; ++i) sd[i] = shapedirs[vc * 30 + i];
    const float vt0 = v_template[vc * 3 + 0];
    const float vt1 = v_template[vc * 3 + 1];
    const float vt2 = v_template[vc * 3 + 2];

    // ---- dump acc -> per-wave LDS region (no cross-wave sharing, no barrier) ----
    float* dspw = &s_disp[wv * 3104];
#pragma unroll
    for (int nt = 0; nt < 12; ++nt) {
#pragma unroll
        for (int r = 0; r < 4; ++r)
            dspw[(g * 4 + r) * 194 + nt * 16 + m] = acc[nt][r];
    }

    const int bw = bbase + __builtin_amdgcn_readfirstlane(wv) * 16;

    // ---- 16 batches per wave: blend A (s_loads) then transform ----
#pragma unroll 1
    for (int bi = 0; bi < 16; ++bi) {
        const int b = bw + bi;                       // wave-uniform -> s_load
        const float* __restrict__ bb = &betas[b * NB_];
        const float* __restrict__ Ab = &A[b * 288];

        float vpx = vt0, vpy = vt1, vpz = vt2;
#pragma unroll
        for (int q = 0; q < NB_; ++q) {
            const float bq = bb[q];
            vpx = fmaf(bq, sd[q],      vpx);
            vpy = fmaf(bq, sd[10 + q], vpy);
            vpz = fmaf(bq, sd[20 + q], vpz);
        }
        vpx += dspw[bi * 194 + 3 * l + 0];
        vpy += dspw[bi * 194 + 3 * l + 1];
        vpz += dspw[bi * 194 + 3 * l + 2];

        float T[12];
#pragma unroll
        for (int e = 0; e < 12; ++e) T[e] = 0.f;
#pragma unroll
        for (int j = 0; j < 24; ++j) {
            const float wj = w24[j];
#pragma unroll
            for (int e = 0; e < 12; ++e) T[e] = fmaf(wj, Ab[j * 12 + e], T[e]);
        }

        const float ox = fmaf(T[0], vpx, fmaf(T[1], vpy, fmaf(T[2],  vpz, T[3])))  + transl[b * 3 + 0];
        const float oy = fmaf(T[4], vpx, fmaf(T[5], vpy, fmaf(T[6],  vpz, T[7])))  + transl[b * 3 + 1];
        const float oz = fmaf(T[8], vpx, fmaf(T[9], vpy, fmaf(T[10], vpz, T[11]))) + transl[b * 3 + 2];

        if (v < V_) {
            float* o = &out[((size_t)b * V_ + v) * 3];
            o[0] = ox; o[1] = oy; o[2] = oz;
        }
    }
}

// ---------------------------------------------------------------------------
extern "C" void kernel_launch(void* const* d_in, const int* in_sizes, int n_in,
                              void* d_out, int out_size, void* d_ws, size_t ws_size,
                              hipStream_t stream)
{
    const float* betas         = (const float*)d_in[0];
    const float* body_pose     = (const float*)d_in[1];
    const float* global_orient = (const float*)d_in[2];
    const float* transl        = (const float*)d_in[3];
    const float* v_template    = (const float*)d_in[4];
    const float* shapedirs     = (const float*)d_in[5];
    const float* posedirs      = (const float*)d_in[6];
    const float* J_regressor   = (const float*)d_in[7];
    const float* lbs_weights   = (const float*)d_in[8];

    float* out = (float*)d_out;
    float* ws  = (float*)d_ws;

    // ws layout (f32 units): JS[720] | JT[72] | A[512*288] | pf bf16 [512*224]
    //                        | pdT bf16 [CPAD*KPAD]
    float* JS  = ws;
    float* JT  = ws + 720;
    float* Aw  = ws + 792;
    unsigned short* pfw = (unsigned short*)(ws + 792 + 147456);
    unsigned short* pdT = (unsigned short*)(ws + 792 + 147456 + 57344);

    const size_t needed = (size_t)(792 + 147456 + 57344) * 4
                        + (size_t)CPAD * KPAD * 2;       // 10,112,096 B
    const bool pre = (ws_size >= needed);

    float* joints = out + (size_t)B_ * V_ * 3;

    k_jreg <<<72, 256, 0, stream>>>(J_regressor, v_template, shapedirs, JS, JT);
    k_pose <<<B_, 64, 0, stream>>>(betas, body_pose, global_orient, transl,
                                   JS, JT, Aw, pfw, joints);
    if (pre) {
        k_cvt<<<dim3(CPAD / 64, 7), 256, 0, stream>>>(posedirs, pdT);
        k_verts<true><<<864, 256, 0, stream>>>(betas, v_template, shapedirs,
                                               posedirs, pdT, lbs_weights, transl,
                                               pfw, Aw, out);
    } else {
        k_verts<false><<<864, 256, 0, stream>>>(betas, v_template, shapedirs,
                                                posedirs, pdT, lbs_weights, transl,
                                                pfw, Aw, out);
    }
}

// Round 4
// 85.860 us; speedup vs baseline: 7.2720x; 1.9921x over previous
//
#include <hip/hip_runtime.h>
#include <math.h>

#define B_    512
#define V_    6890
#define J_    24
#define NB_   10
#define K_    207     // 9*(J-1)
#define KPAD  224     // 7 chunks of 32; slots 207..216 = betas x shapedirs
#define NCOL  20670   // V*3
#define CPAD  20736   // 108 vtiles * 192 cols

typedef __attribute__((ext_vector_type(8))) __bf16 bf16x8;
typedef __attribute__((ext_vector_type(4))) float  f32x4;

__constant__ int c_par[24] = {-1,0,0,0,1,2,3,4,5,6,7,8,9,9,9,12,13,14,16,17,18,19,20,21};
__constant__ int c_lev[24] = { 0,1,1,1,2,2,2,3,3,3,4,4,4,4,4, 5, 5, 5, 6, 6, 7, 7, 8, 8};

__device__ __forceinline__ unsigned short f2bf(float x) {
    union { float f; unsigned u; } v; v.f = x;
    unsigned r = (v.u + 0x7FFFu + ((v.u >> 16) & 1u)) >> 16;
    return (unsigned short)r;
}
__device__ __forceinline__ float bf2f(unsigned short h) {
    union { unsigned u; float f; } v; v.u = (unsigned)h << 16;
    return v.f;
}

// ---------------------------------------------------------------------------
// K0: one-time build of pdT bf16 [CPAD][KPAD]:
//   k<207: posedirs[k][c];  207..216: shapedirs[c][k-207];  217..223: 0
// grid (CPAD/64, 7) x 256.
// ---------------------------------------------------------------------------
__global__ __launch_bounds__(256) void k_cvt(const float* __restrict__ pd,
                                             const float* __restrict__ sd,
                                             unsigned short* __restrict__ pdT)
{
    const int c  = blockIdx.x * 64 + (threadIdx.x & 63);
    const int kq = blockIdx.y * 4 + (threadIdx.x >> 6);   // 0..27
    unsigned short u[8];
#pragma unroll
    for (int e = 0; e < 8; ++e) {
        const int k = kq * 8 + e;
        float x = 0.f;
        if (c < NCOL) {
            if (k < K_)            x = pd[(size_t)k * NCOL + c];
            else if (k < K_ + NB_) x = sd[(size_t)c * NB_ + (k - K_)];
        }
        u[e] = f2bf(x);
    }
    *reinterpret_cast<uint4*>(&pdT[(size_t)c * KPAD + kq * 8]) =
        *reinterpret_cast<const uint4*>(u);
}

// ---------------------------------------------------------------------------
// K1: JT[j][k] = sum_v Jreg[j][v]*vt[v][k];  JS[j][k][l] = sum_v Jreg[j][v]*sd[v][k][l]
// ---------------------------------------------------------------------------
__global__ __launch_bounds__(256) void k_jreg(const float* __restrict__ Jreg,
                                              const float* __restrict__ vt,
                                              const float* __restrict__ sd,
                                              float* __restrict__ JS,
                                              float* __restrict__ JT)
{
    const int j = blockIdx.x / 3, k = blockIdx.x % 3;
    const int tid = threadIdx.x;
    float acc[11];
#pragma unroll
    for (int i = 0; i < 11; ++i) acc[i] = 0.f;

    for (int v = tid; v < V_; v += 256) {
        const float r = Jreg[j * V_ + v];
        acc[0] = fmaf(r, vt[v * 3 + k], acc[0]);
        const float* s = &sd[(v * 3 + k) * NB_];
#pragma unroll
        for (int l = 0; l < NB_; ++l) acc[1 + l] = fmaf(r, s[l], acc[1 + l]);
    }

    __shared__ float red[4][11];
    const int lane = tid & 63, w = tid >> 6;
#pragma unroll
    for (int i = 0; i < 11; ++i) {
        float a = acc[i];
        for (int off = 32; off; off >>= 1) a += __shfl_xor(a, off, 64);
        acc[i] = a;
    }
    if (lane == 0) {
#pragma unroll
        for (int i = 0; i < 11; ++i) red[w][i] = acc[i];
    }
    __syncthreads();
    if (tid == 0) {
        for (int i = 0; i < 11; ++i) {
            const float s = red[0][i] + red[1][i] + red[2][i] + red[3][i];
            if (i == 0) JT[j * 3 + k] = s;
            else        JS[(j * 3 + k) * NB_ + (i - 1)] = s;
        }
    }
}

// ---------------------------------------------------------------------------
// K2: per-batch joint pipeline. grid = 512, block = 64.
// Writes:
//   pf bf16 [B][KPAD]: pose features 0..206, betas 207..216, zeros 217..223
//   At bf16 [B*16][64]: rows e=4*r+cc (pad to 16) of A_aug (transl folded into
//     translation column), cols j (pad 24->32), split hi|lo at col offset 32
//   joints output (+transl)
// ---------------------------------------------------------------------------
__global__ __launch_bounds__(64) void k_pose(const float* __restrict__ betas,
                                             const float* __restrict__ body_pose,
                                             const float* __restrict__ global_orient,
                                             const float* __restrict__ transl,
                                             const float* __restrict__ JS,
                                             const float* __restrict__ JT,
                                             unsigned short* __restrict__ Atout,
                                             unsigned short* __restrict__ pfout,
                                             float* __restrict__ joints_out)
{
    const int b = blockIdx.x;
    const int j = threadIdx.x;

    __shared__ float sR[24][9];
    __shared__ float sJ[24][3];
    __shared__ float sTl[24][12];
    __shared__ float sTg[24][12];

    if (j < 24) {
        float rx, ry, rz;
        if (j == 0) {
            rx = global_orient[b * 3 + 0];
            ry = global_orient[b * 3 + 1];
            rz = global_orient[b * 3 + 2];
        } else {
            const float* p = &body_pose[b * 69 + (j - 1) * 3];
            rx = p[0]; ry = p[1]; rz = p[2];
        }
        const float ax = rx + 1e-8f, ay = ry + 1e-8f, az = rz + 1e-8f;
        const float angle = sqrtf(ax * ax + ay * ay + az * az);
        const float inv = 1.f / angle;
        const float x = rx * inv, y = ry * inv, z = rz * inv;
        const float s = sinf(angle), c = cosf(angle), t = 1.f - c;

        float R[9];
        R[0] = 1.f - t * (y * y + z * z);
        R[1] = -s * z + t * x * y;
        R[2] =  s * y + t * x * z;
        R[3] =  s * z + t * x * y;
        R[4] = 1.f - t * (x * x + z * z);
        R[5] = -s * x + t * y * z;
        R[6] = -s * y + t * x * z;
        R[7] =  s * x + t * y * z;
        R[8] = 1.f - t * (x * x + y * y);

#pragma unroll
        for (int e = 0; e < 9; ++e) sR[j][e] = R[e];

        if (j >= 1) {
#pragma unroll
            for (int e = 0; e < 9; ++e) {
                const float id = (e == 0 || e == 4 || e == 8) ? 1.f : 0.f;
                pfout[b * KPAD + (j - 1) * 9 + e] = f2bf(R[e] - id);
            }
        }
#pragma unroll
        for (int k = 0; k < 3; ++k) {
            float jr = JT[j * 3 + k];
#pragma unroll
            for (int l = 0; l < NB_; ++l)
                jr = fmaf(betas[b * NB_ + l], JS[(j * 3 + k) * NB_ + l], jr);
            sJ[j][k] = jr;
        }
    }
    // pf tail: betas at 207..216, zeros 217..223
    if (j < KPAD - K_) {
        const float val = (j < NB_) ? betas[b * NB_ + j] : 0.f;
        pfout[b * KPAD + K_ + j] = f2bf(val);
    }
    __syncthreads();

    if (j < 24) {
        const int p = c_par[j];
        float t0 = sJ[j][0], t1 = sJ[j][1], t2 = sJ[j][2];
        if (j > 0) { t0 -= sJ[p][0]; t1 -= sJ[p][1]; t2 -= sJ[p][2]; }
        sTl[j][0] = sR[j][0]; sTl[j][1] = sR[j][1]; sTl[j][2]  = sR[j][2]; sTl[j][3]  = t0;
        sTl[j][4] = sR[j][3]; sTl[j][5] = sR[j][4]; sTl[j][6]  = sR[j][5]; sTl[j][7]  = t1;
        sTl[j][8] = sR[j][6]; sTl[j][9] = sR[j][7]; sTl[j][10] = sR[j][8]; sTl[j][11] = t2;
    }
    __syncthreads();

    if (j == 0) {
#pragma unroll
        for (int e = 0; e < 12; ++e) sTg[0][e] = sTl[0][e];
    }
    __syncthreads();

    for (int lev = 1; lev <= 8; ++lev) {
        if (j < 24 && c_lev[j] == lev) {
            const int p = c_par[j];
            float o[12];
#pragma unroll
            for (int r = 0; r < 3; ++r) {
#pragma unroll
                for (int c = 0; c < 4; ++c) {
                    float v = (c == 3) ? sTg[p][r * 4 + 3] : 0.f;
#pragma unroll
                    for (int m = 0; m < 3; ++m)
                        v = fmaf(sTg[p][r * 4 + m], sTl[j][m * 4 + c], v);
                    o[r * 4 + c] = v;
                }
            }
#pragma unroll
            for (int e = 0; e < 12; ++e) sTg[j][e] = o[e];
        }
        __syncthreads();
    }

    if (j < 24) {
        float corr[3];
#pragma unroll
        for (int r = 0; r < 3; ++r)
            corr[r] = sTg[j][r * 4 + 0] * sJ[j][0] + sTg[j][r * 4 + 1] * sJ[j][1]
                    + sTg[j][r * 4 + 2] * sJ[j][2];

        // split-bf16 A rows, transl folded into translation column (sum_j w = 1)
#pragma unroll
        for (int r = 0; r < 3; ++r) {
            float row[4];
            row[0] = sTg[j][r * 4 + 0];
            row[1] = sTg[j][r * 4 + 1];
            row[2] = sTg[j][r * 4 + 2];
            row[3] = sTg[j][r * 4 + 3] - corr[r] + transl[b * 3 + r];
#pragma unroll
            for (int cc = 0; cc < 4; ++cc) {
                const float val = row[cc];
                const unsigned short hi = f2bf(val);
                const unsigned short lo = f2bf(val - bf2f(hi));
                const size_t base = ((size_t)b * 16 + r * 4 + cc) * 64;
                Atout[base + j]      = hi;
                Atout[base + 32 + j] = lo;
            }
        }
#pragma unroll
        for (int k = 0; k < 3; ++k)
            joints_out[(b * 24 + j) * 3 + k] = sTg[j][k * 4 + 3] + transl[b * 3 + k];
    }
    // zero-fill At padding: rows e=12..15 (all cols), cols j=24..31 per half
    for (int idx = j; idx < 1024; idx += 64) {
        const int e = idx >> 6, jj = idx & 63;
        if (e >= 12 || (jj & 31) >= 24)
            Atout[((size_t)b * 16 + e) * 64 + jj] = 0;
    }
}

// ---------------------------------------------------------------------------
// K3: all-MFMA vertex kernel. grid = 864 (XCD-chunked), block = 256 (4 waves).
// GEMM1: v_posed[b][c] = pf[b][:] @ pdT[c][:]  (pose disp + shape blend),
//        + v_template added at dump. Lane(m,g): rows b_loc=g*4+r, col nt*16+m.
// GEMM2: per batch mt: D[e][v] = At[b,e,:] @ W[v,:]^T; lane(m,g) holds
//        T-row g (4 elems) for vertex v=nt*16+m -> out = T.vh locally.
// LDS: s_w 4 KB + s_vp 4x16x192 f32 = 53.25 KB -> 3 blocks/CU.
// ---------------------------------------------------------------------------
template<bool PRE>
__global__ __launch_bounds__(256, 3) void k_verts(
    const float* __restrict__ v_template,        // flat [NCOL]
    const float* __restrict__ posedirs,          // fallback only
    const float* __restrict__ shapedirs,         // fallback only
    const unsigned short* __restrict__ pdT,      // bf16 [CPAD][KPAD]
    const float* __restrict__ lbs_weights,       // [V][24]
    const unsigned short* __restrict__ pf,       // bf16 [B][KPAD]
    const unsigned short* __restrict__ At,       // bf16 [B*16][64] hi|lo
    float* __restrict__ out)                     // [B][V][3]
{
    __shared__ unsigned short s_w[64 * 32];      // W bf16 [v][j pad32]
    __shared__ float s_vp[4 * 16 * 192];         // per-wave v_posed [16 b][192 c]

    const int tid = threadIdx.x;
    const int l   = tid & 63;
    const int wv  = tid >> 6;
    const int m   = l & 15;
    const int g   = l >> 4;

    // XCD-chunked remap (864 % 8 == 0 -> bijective)
    const int lraw  = blockIdx.x;
    const int gl    = (lraw & 7) * 108 + (lraw >> 3);
    const int vtile = gl >> 3;
    const int btile = gl & 7;
    const int vbase = vtile * 64;
    const int bbase = btile * 64;
    const int vb3   = vtile * 192;

    // ---- stage W: lbs_weights[vbase+v][j] -> bf16 [64][32] ----
    {
        const int v  = tid >> 2, jq = tid & 3;
        const int vv = vbase + v;
        const int vc = vv < V_ ? vv : V_ - 1;
        unsigned short u[8];
        if (jq < 3) {
            const float* src = &lbs_weights[vc * 24 + jq * 8];
#pragma unroll
            for (int e = 0; e < 8; ++e) u[e] = f2bf(src[e]);
        } else {
#pragma unroll
            for (int e = 0; e < 8; ++e) u[e] = 0;
        }
        *reinterpret_cast<uint4*>(&s_w[v * 32 + jq * 8]) =
            *reinterpret_cast<const uint4*>(u);
    }
    __syncthreads();

    // ---- GEMM1 ----
    f32x4 acc1[12];
#pragma unroll
    for (int i = 0; i < 12; ++i) acc1[i] = (f32x4){0.f, 0.f, 0.f, 0.f};

#pragma unroll 1
    for (int kc = 0; kc < KPAD; kc += 32) {
        const bf16x8 af = *reinterpret_cast<const bf16x8*>(
            &pf[(size_t)(bbase + wv * 16 + m) * KPAD + kc + g * 8]);
        if (PRE) {
#pragma unroll
            for (int nt = 0; nt < 12; ++nt) {
                const bf16x8 bfr = *reinterpret_cast<const bf16x8*>(
                    &pdT[(size_t)(vb3 + nt * 16 + m) * KPAD + kc + g * 8]);
                acc1[nt] = __builtin_amdgcn_mfma_f32_16x16x32_bf16(af, bfr, acc1[nt], 0, 0, 0);
            }
        } else {
#pragma unroll
            for (int nt = 0; nt < 12; ++nt) {
                unsigned short u[8];
                const int c = vb3 + nt * 16 + m;
#pragma unroll
                for (int e = 0; e < 8; ++e) {
                    const int k = kc + g * 8 + e;
                    float x = 0.f;
                    if (c < NCOL) {
                        if (k < K_)            x = posedirs[(size_t)k * NCOL + c];
                        else if (k < K_ + NB_) x = shapedirs[(size_t)c * NB_ + (k - K_)];
                    }
                    u[e] = f2bf(x);
                }
                const bf16x8 bfr = *reinterpret_cast<const bf16x8*>(u);
                acc1[nt] = __builtin_amdgcn_mfma_f32_16x16x32_bf16(af, bfr, acc1[nt], 0, 0, 0);
            }
        }
    }

    // ---- dump v_posed (+v_template, f32 exact) into per-wave LDS ----
    float* vp = &s_vp[wv * 16 * 192];
#pragma unroll
    for (int nt = 0; nt < 12; ++nt) {
        const int c = vb3 + nt * 16 + m;
        const float vtf = (c < NCOL) ? v_template[c] : 0.f;
#pragma unroll
        for (int r = 0; r < 4; ++r)
            vp[(g * 4 + r) * 192 + nt * 16 + m] = acc1[nt][r] + vtf;
    }

    // ---- W B-frags (reused across all 16 batches) ----
    bf16x8 wf[4];
#pragma unroll
    for (int nt = 0; nt < 4; ++nt)
        wf[nt] = *reinterpret_cast<const bf16x8*>(&s_w[(nt * 16 + m) * 32 + g * 8]);

    // ---- GEMM2 + combine: one batch per m-tile ----
#pragma unroll 2
    for (int mt = 0; mt < 16; ++mt) {
        const int b = bbase + wv * 16 + mt;
        const size_t arow = ((size_t)b * 16 + m) * 64;
        const bf16x8 ahi = *reinterpret_cast<const bf16x8*>(&At[arow + g * 8]);
        const bf16x8 alo = *reinterpret_cast<const bf16x8*>(&At[arow + 32 + g * 8]);
#pragma unroll
        for (int nt = 0; nt < 4; ++nt) {
            f32x4 t = (f32x4){0.f, 0.f, 0.f, 0.f};
            t = __builtin_amdgcn_mfma_f32_16x16x32_bf16(ahi, wf[nt], t, 0, 0, 0);
            t = __builtin_amdgcn_mfma_f32_16x16x32_bf16(alo, wf[nt], t, 0, 0, 0);
            const float vpx = vp[mt * 192 + nt * 48 + 3 * m + 0];
            const float vpy = vp[mt * 192 + nt * 48 + 3 * m + 1];
            const float vpz = vp[mt * 192 + nt * 48 + 3 * m + 2];
            const float o = fmaf(t[0], vpx, fmaf(t[1], vpy, fmaf(t[2], vpz, t[3])));
            const int vv = vbase + nt * 16 + m;
            if (g < 3 && vv < V_)
                out[((size_t)b * V_ + vv) * 3 + g] = o;
        }
    }
}

// ---------------------------------------------------------------------------
extern "C" void kernel_launch(void* const* d_in, const int* in_sizes, int n_in,
                              void* d_out, int out_size, void* d_ws, size_t ws_size,
                              hipStream_t stream)
{
    const float* betas         = (const float*)d_in[0];
    const float* body_pose     = (const float*)d_in[1];
    const float* global_orient = (const float*)d_in[2];
    const float* transl        = (const float*)d_in[3];
    const float* v_template    = (const float*)d_in[4];
    const float* shapedirs     = (const float*)d_in[5];
    const float* posedirs      = (const float*)d_in[6];
    const float* J_regressor   = (const float*)d_in[7];
    const float* lbs_weights   = (const float*)d_in[8];

    float* out = (float*)d_out;
    float* ws  = (float*)d_ws;

    // ws layout: JS[720] JT[72] f32 | pf bf16 [512*224] | At bf16 [8192*64]
    //            | pdT bf16 [CPAD*224]
    float* JS = ws;
    float* JT = ws + 720;
    unsigned short* pfw = (unsigned short*)(ws + 792);
    unsigned short* Atw = pfw + (size_t)B_ * KPAD;       // 114,688 bf16
    unsigned short* pdT = Atw + (size_t)B_ * 16 * 64;    // +524,288 bf16

    const size_t needed_pre = 792u * 4 + (size_t)B_ * KPAD * 2
                            + (size_t)B_ * 16 * 64 * 2
                            + (size_t)CPAD * KPAD * 2;   // ~10.57 MB
    const bool pre = (ws_size >= needed_pre);

    float* joints = out + (size_t)B_ * V_ * 3;

    k_jreg <<<72, 256, 0, stream>>>(J_regressor, v_template, shapedirs, JS, JT);
    k_pose <<<B_, 64, 0, stream>>>(betas, body_pose, global_orient, transl,
                                   JS, JT, Atw, pfw, joints);
    if (pre) {
        k_cvt<<<dim3(CPAD / 64, 7), 256, 0, stream>>>(posedirs, shapedirs, pdT);
        k_verts<true><<<864, 256, 0, stream>>>(v_template, posedirs, shapedirs,
                                               pdT, lbs_weights, pfw, Atw, out);
    } else {
        k_verts<false><<<864, 256, 0, stream>>>(v_template, posedirs, shapedirs,
                                                pdT, lbs_weights, pfw, Atw, out);
    }
}

// Round 5
// 66.616 us; speedup vs baseline: 9.3728x; 1.2889x over previous
//
#include <hip/hip_runtime.h>
#include <math.h>

#define B_    512
#define V_    6890
#define J_    24
#define NB_   10
#define K_    207     // 9*(J-1)
#define KPAD  224     // 7 chunks of 32; slots 207..216 = betas x shapedirs
#define NCOL  20670   // V*3
#define CPAD  20736   // 108 vtiles * 192 cols
#define NCVT  2268    // (CPAD/64) * 7 blocks in k_prep

typedef __attribute__((ext_vector_type(8))) __bf16 bf16x8;
typedef __attribute__((ext_vector_type(4))) float  f32x4;

__constant__ int c_par[24] = {-1,0,0,0,1,2,3,4,5,6,7,8,9,9,9,12,13,14,16,17,18,19,20,21};
__constant__ int c_lev[24] = { 0,1,1,1,2,2,2,3,3,3,4,4,4,4,4, 5, 5, 5, 6, 6, 7, 7, 8, 8};

__device__ __forceinline__ unsigned short f2bf(float x) {
    union { float f; unsigned u; } v; v.f = x;
    unsigned r = (v.u + 0x7FFFu + ((v.u >> 16) & 1u)) >> 16;
    return (unsigned short)r;
}
__device__ __forceinline__ float bf2f(unsigned short h) {
    union { unsigned u; float f; } v; v.u = (unsigned)h << 16;
    return v.f;
}
// wave-internal LDS fence: lockstep wave64 + drained lgkm = all lanes' ds ops done
__device__ __forceinline__ void wsync() {
    asm volatile("s_waitcnt lgkmcnt(0)" ::: "memory");
}

// ---------------------------------------------------------------------------
// K0 (fused): blocks [0, NCVT): posedirs/shapedirs -> pdT bf16 [CPAD][KPAD]
//             blocks [NCVT, NCVT+72): JT/JS reduction (old k_jreg)
// ---------------------------------------------------------------------------
__global__ __launch_bounds__(256) void k_prep(const float* __restrict__ pd,
                                              const float* __restrict__ sd,
                                              const float* __restrict__ Jreg,
                                              const float* __restrict__ vt,
                                              unsigned short* __restrict__ pdT,
                                              float* __restrict__ JS,
                                              float* __restrict__ JT,
                                              int do_cvt)
{
    __shared__ float red[4][11];
    const int tid = threadIdx.x;
    const int bx  = blockIdx.x;

    if (bx < NCVT) {
        if (!do_cvt) return;
        const int c  = (bx % 324) * 64 + (tid & 63);
        const int kq = (bx / 324) * 4 + (tid >> 6);   // 0..27
        unsigned short u[8];
#pragma unroll
        for (int e = 0; e < 8; ++e) {
            const int k = kq * 8 + e;
            float x = 0.f;
            if (c < NCOL) {
                if (k < K_)            x = pd[(size_t)k * NCOL + c];
                else if (k < K_ + NB_) x = sd[(size_t)c * NB_ + (k - K_)];
            }
            u[e] = f2bf(x);
        }
        *reinterpret_cast<uint4*>(&pdT[(size_t)c * KPAD + kq * 8]) =
            *reinterpret_cast<const uint4*>(u);
        return;
    }

    // ---- jreg part ----
    const int jk = bx - NCVT;           // 0..71
    const int j = jk / 3, k = jk % 3;
    float acc[11];
#pragma unroll
    for (int i = 0; i < 11; ++i) acc[i] = 0.f;

    for (int v = tid; v < V_; v += 256) {
        const float r = Jreg[j * V_ + v];
        acc[0] = fmaf(r, vt[v * 3 + k], acc[0]);
        const float* s = &sd[(v * 3 + k) * NB_];
#pragma unroll
        for (int l = 0; l < NB_; ++l) acc[1 + l] = fmaf(r, s[l], acc[1 + l]);
    }

    const int lane = tid & 63, w = tid >> 6;
#pragma unroll
    for (int i = 0; i < 11; ++i) {
        float a = acc[i];
        for (int off = 32; off; off >>= 1) a += __shfl_xor(a, off, 64);
        acc[i] = a;
    }
    if (lane == 0) {
#pragma unroll
        for (int i = 0; i < 11; ++i) red[w][i] = acc[i];
    }
    __syncthreads();
    if (tid == 0) {
        for (int i = 0; i < 11; ++i) {
            const float s = red[0][i] + red[1][i] + red[2][i] + red[3][i];
            if (i == 0) JT[j * 3 + k] = s;
            else        JS[(j * 3 + k) * NB_ + (i - 1)] = s;
        }
    }
}

// ---------------------------------------------------------------------------
// K2: joint pipeline, one WAVE per batch (no block barriers). grid=128 x 256.
// ---------------------------------------------------------------------------
__global__ __launch_bounds__(256) void k_pose(const float* __restrict__ betas,
                                              const float* __restrict__ body_pose,
                                              const float* __restrict__ global_orient,
                                              const float* __restrict__ transl,
                                              const float* __restrict__ JS,
                                              const float* __restrict__ JT,
                                              unsigned short* __restrict__ Atout,
                                              unsigned short* __restrict__ pfout,
                                              float* __restrict__ joints_out)
{
    const int wv   = threadIdx.x >> 6;
    const int lane = threadIdx.x & 63;
    const int b    = blockIdx.x * 4 + wv;
    const int j    = lane;

    __shared__ float sR[4][24][9];
    __shared__ float sJ[4][24][3];
    __shared__ float sTl[4][24][12];
    __shared__ float sTg[4][24][12];

    if (j < 24) {
        float rx, ry, rz;
        if (j == 0) {
            rx = global_orient[b * 3 + 0];
            ry = global_orient[b * 3 + 1];
            rz = global_orient[b * 3 + 2];
        } else {
            const float* p = &body_pose[b * 69 + (j - 1) * 3];
            rx = p[0]; ry = p[1]; rz = p[2];
        }
        const float ax = rx + 1e-8f, ay = ry + 1e-8f, az = rz + 1e-8f;
        const float angle = sqrtf(ax * ax + ay * ay + az * az);
        const float inv = 1.f / angle;
        const float x = rx * inv, y = ry * inv, z = rz * inv;
        const float s = sinf(angle), c = cosf(angle), t = 1.f - c;

        float R[9];
        R[0] = 1.f - t * (y * y + z * z);
        R[1] = -s * z + t * x * y;
        R[2] =  s * y + t * x * z;
        R[3] =  s * z + t * x * y;
        R[4] = 1.f - t * (x * x + z * z);
        R[5] = -s * x + t * y * z;
        R[6] = -s * y + t * x * z;
        R[7] =  s * x + t * y * z;
        R[8] = 1.f - t * (x * x + y * y);

#pragma unroll
        for (int e = 0; e < 9; ++e) sR[wv][j][e] = R[e];

        if (j >= 1) {
#pragma unroll
            for (int e = 0; e < 9; ++e) {
                const float id = (e == 0 || e == 4 || e == 8) ? 1.f : 0.f;
                pfout[b * KPAD + (j - 1) * 9 + e] = f2bf(R[e] - id);
            }
        }
#pragma unroll
        for (int k = 0; k < 3; ++k) {
            float jr = JT[j * 3 + k];
#pragma unroll
            for (int l = 0; l < NB_; ++l)
                jr = fmaf(betas[b * NB_ + l], JS[(j * 3 + k) * NB_ + l], jr);
            sJ[wv][j][k] = jr;
        }
    }
    if (j < KPAD - K_) {
        const float val = (j < NB_) ? betas[b * NB_ + j] : 0.f;
        pfout[b * KPAD + K_ + j] = f2bf(val);
    }
    wsync();

    if (j < 24) {
        const int p = c_par[j];
        float t0 = sJ[wv][j][0], t1 = sJ[wv][j][1], t2 = sJ[wv][j][2];
        if (j > 0) { t0 -= sJ[wv][p][0]; t1 -= sJ[wv][p][1]; t2 -= sJ[wv][p][2]; }
        sTl[wv][j][0] = sR[wv][j][0]; sTl[wv][j][1] = sR[wv][j][1];
        sTl[wv][j][2] = sR[wv][j][2]; sTl[wv][j][3] = t0;
        sTl[wv][j][4] = sR[wv][j][3]; sTl[wv][j][5] = sR[wv][j][4];
        sTl[wv][j][6] = sR[wv][j][5]; sTl[wv][j][7] = t1;
        sTl[wv][j][8] = sR[wv][j][6]; sTl[wv][j][9] = sR[wv][j][7];
        sTl[wv][j][10] = sR[wv][j][8]; sTl[wv][j][11] = t2;
    }
    wsync();

    if (j == 0) {
#pragma unroll
        for (int e = 0; e < 12; ++e) sTg[wv][0][e] = sTl[wv][0][e];
    }
    wsync();

    for (int lev = 1; lev <= 8; ++lev) {
        if (j < 24 && c_lev[j] == lev) {
            const int p = c_par[j];
            float o[12];
#pragma unroll
            for (int r = 0; r < 3; ++r) {
#pragma unroll
                for (int c = 0; c < 4; ++c) {
                    float v = (c == 3) ? sTg[wv][p][r * 4 + 3] : 0.f;
#pragma unroll
                    for (int m = 0; m < 3; ++m)
                        v = fmaf(sTg[wv][p][r * 4 + m], sTl[wv][j][m * 4 + c], v);
                    o[r * 4 + c] = v;
                }
            }
#pragma unroll
            for (int e = 0; e < 12; ++e) sTg[wv][j][e] = o[e];
        }
        wsync();
    }

    if (j < 24) {
        float corr[3];
#pragma unroll
        for (int r = 0; r < 3; ++r)
            corr[r] = sTg[wv][j][r * 4 + 0] * sJ[wv][j][0]
                    + sTg[wv][j][r * 4 + 1] * sJ[wv][j][1]
                    + sTg[wv][j][r * 4 + 2] * sJ[wv][j][2];

#pragma unroll
        for (int r = 0; r < 3; ++r) {
            float row[4];
            row[0] = sTg[wv][j][r * 4 + 0];
            row[1] = sTg[wv][j][r * 4 + 1];
            row[2] = sTg[wv][j][r * 4 + 2];
            row[3] = sTg[wv][j][r * 4 + 3] - corr[r] + transl[b * 3 + r];
#pragma unroll
            for (int cc = 0; cc < 4; ++cc) {
                const float val = row[cc];
                const unsigned short hi = f2bf(val);
                const unsigned short lo = f2bf(val - bf2f(hi));
                const size_t base = ((size_t)b * 16 + r * 4 + cc) * 64;
                Atout[base + j]      = hi;
                Atout[base + 32 + j] = lo;
            }
        }
#pragma unroll
        for (int k = 0; k < 3; ++k)
            joints_out[(b * 24 + j) * 3 + k] = sTg[wv][j][k * 4 + 3] + transl[b * 3 + k];
    }
    for (int idx = j; idx < 1024; idx += 64) {
        const int e = idx >> 6, jj = idx & 63;
        if (e >= 12 || (jj & 31) >= 24)
            Atout[((size_t)b * 16 + e) * 64 + jj] = 0;
    }
}

// ---------------------------------------------------------------------------
// K3: MFMA vertex kernel, LDS-staged pdT (double-buffered, block-shared).
// grid = 864 (XCD-chunked), block = 256 (4 waves), 4 blocks/CU.
// LDS: s_pd 2 x [192][40] bf16 = 30720 B (aliased by s_vp [4][8][192] f32
//      = 24576 B in epilogue) + s_w 4096 B  => 34816 B total.
// ---------------------------------------------------------------------------
template<bool PRE>
__global__ __launch_bounds__(256, 4) void k_verts(
    const float* __restrict__ v_template,        // flat [NCOL]
    const float* __restrict__ posedirs,          // fallback staging source
    const float* __restrict__ shapedirs,         // fallback staging source
    const unsigned short* __restrict__ pdT,      // bf16 [CPAD][KPAD]
    const float* __restrict__ lbs_weights,       // [V][24]
    const unsigned short* __restrict__ pf,       // bf16 [B][KPAD]
    const unsigned short* __restrict__ At,       // bf16 [B*16][64] hi|lo
    float* __restrict__ out)                     // [B][V][3]
{
    __shared__ __align__(16) char smem[30720 + 4096];
    unsigned short* s_pd = (unsigned short*)smem;           // 2 bufs x 7680 halves
    unsigned short* s_w  = (unsigned short*)(smem + 30720); // [64][32]
    float*          s_vp = (float*)smem;                    // alias: [4][8][192]

    const int tid = threadIdx.x;
    const int l   = tid & 63;
    const int wv  = tid >> 6;
    const int m   = l & 15;
    const int g   = l >> 4;

    const int lraw  = blockIdx.x;                 // 864 % 8 == 0 -> bijective
    const int gl    = (lraw & 7) * 108 + (lraw >> 3);
    const int vtile = gl >> 3;
    const int btile = gl & 7;
    const int vbase = vtile * 64;
    const int bbase = btile * 64;
    const int vb3   = vtile * 192;

    // ---- stage W once: lbs_weights -> bf16 [64][32] ----
    {
        const int v  = tid >> 2, jq = tid & 3;
        const int vv = vbase + v;
        const int vc = vv < V_ ? vv : V_ - 1;
        unsigned short u[8];
        if (jq < 3) {
            const float* src = &lbs_weights[vc * 24 + jq * 8];
#pragma unroll
            for (int e = 0; e < 8; ++e) u[e] = f2bf(src[e]);
        } else {
#pragma unroll
            for (int e = 0; e < 8; ++e) u[e] = 0;
        }
        *reinterpret_cast<uint4*>(&s_w[v * 32 + jq * 8]) =
            *reinterpret_cast<const uint4*>(u);
    }

    // staging helpers: chunk = [192 cols][32 k] -> s_pd[buf], stride 40 halves
    auto ld_chunk = [&](int kc, int it, uint4& dst) {
        const int idx = it * 256 + tid;
        const int col = idx >> 2, g4 = idx & 3;
        if (PRE) {
            dst = *reinterpret_cast<const uint4*>(
                &pdT[(size_t)(vb3 + col) * KPAD + kc + g4 * 8]);
        } else {
            unsigned short u[8];
            const int c = vb3 + col;
#pragma unroll
            for (int e = 0; e < 8; ++e) {
                const int k = kc + g4 * 8 + e;
                float x = 0.f;
                if (c < NCOL) {
                    if (k < K_)            x = posedirs[(size_t)k * NCOL + c];
                    else if (k < K_ + NB_) x = shapedirs[(size_t)c * NB_ + (k - K_)];
                }
                u[e] = f2bf(x);
            }
            dst = *reinterpret_cast<const uint4*>(u);
        }
    };
    auto st_chunk = [&](int buf, int it, const uint4& v) {
        const int idx = it * 256 + tid;
        const int col = idx >> 2, g4 = idx & 3;
        *reinterpret_cast<uint4*>(&s_pd[buf * 7680 + col * 40 + g4 * 8]) = v;
    };

    // ---- prologue: stage chunk 0 into buf 0 ----
    {
        uint4 t0, t1, t2;
        ld_chunk(0, 0, t0); ld_chunk(0, 1, t1); ld_chunk(0, 2, t2);
        st_chunk(0, 0, t0); st_chunk(0, 1, t1); st_chunk(0, 2, t2);
    }
    __syncthreads();

    f32x4 acc1[12];
#pragma unroll
    for (int i = 0; i < 12; ++i) acc1[i] = (f32x4){0.f, 0.f, 0.f, 0.f};

    // ---- GEMM1: 7 chunks, T14 issue-early / write-late double buffer ----
    int cur = 0;
#pragma unroll 1
    for (int ck = 0; ck < 7; ++ck) {
        uint4 t0, t1, t2;
        if (ck < 6) {                        // issue next-chunk loads first
            ld_chunk((ck + 1) * 32, 0, t0);
            ld_chunk((ck + 1) * 32, 1, t1);
            ld_chunk((ck + 1) * 32, 2, t2);
        }
        const bf16x8 af = *reinterpret_cast<const bf16x8*>(
            &pf[(size_t)(bbase + wv * 16 + m) * KPAD + ck * 32 + g * 8]);
        const unsigned short* pb = &s_pd[cur * 7680 + m * 40 + g * 8];
#pragma unroll
        for (int nt = 0; nt < 12; ++nt) {
            const bf16x8 bfr = *reinterpret_cast<const bf16x8*>(&pb[nt * 640]);
            acc1[nt] = __builtin_amdgcn_mfma_f32_16x16x32_bf16(af, bfr, acc1[nt], 0, 0, 0);
        }
        if (ck < 6) {                        // write-late (waits vmcnt internally)
            st_chunk(cur ^ 1, 0, t0);
            st_chunk(cur ^ 1, 1, t1);
            st_chunk(cur ^ 1, 2, t2);
        }
        __syncthreads();
        cur ^= 1;
    }
    // after final barrier: no more s_pd reads; s_vp may alias it.

    // ---- W B-frags (registers, reused across all batches) ----
    bf16x8 wf[4];
#pragma unroll
    for (int nt = 0; nt < 4; ++nt)
        wf[nt] = *reinterpret_cast<const bf16x8*>(&s_w[(nt * 16 + m) * 32 + g * 8]);

    float* vp = &s_vp[wv * 8 * 192];         // per-wave private 8-row buffer

    // ---- two halves: dump 8 batch-rows of v_posed, then GEMM2 on them ----
#pragma unroll 1
    for (int h = 0; h < 2; ++h) {
        if ((g >> 1) == h) {
            const int r4 = (g & 1) * 4;
#pragma unroll
            for (int nt = 0; nt < 12; ++nt) {
                const int c = vb3 + nt * 16 + m;
                const float vtf = (c < NCOL) ? v_template[c] : 0.f;
#pragma unroll
                for (int r = 0; r < 4; ++r)
                    vp[(r4 + r) * 192 + nt * 16 + m] = acc1[nt][r] + vtf;
            }
        }
        wsync();

#pragma unroll 2
        for (int mt8 = 0; mt8 < 8; ++mt8) {
            const int b = bbase + wv * 16 + h * 8 + mt8;
            const size_t arow = ((size_t)b * 16 + m) * 64;
            const bf16x8 ahi = *reinterpret_cast<const bf16x8*>(&At[arow + g * 8]);
            const bf16x8 alo = *reinterpret_cast<const bf16x8*>(&At[arow + 32 + g * 8]);
#pragma unroll
            for (int nt = 0; nt < 4; ++nt) {
                f32x4 t = (f32x4){0.f, 0.f, 0.f, 0.f};
                t = __builtin_amdgcn_mfma_f32_16x16x32_bf16(ahi, wf[nt], t, 0, 0, 0);
                t = __builtin_amdgcn_mfma_f32_16x16x32_bf16(alo, wf[nt], t, 0, 0, 0);
                const float vpx = vp[mt8 * 192 + nt * 48 + 3 * m + 0];
                const float vpy = vp[mt8 * 192 + nt * 48 + 3 * m + 1];
                const float vpz = vp[mt8 * 192 + nt * 48 + 3 * m + 2];
                const float o = fmaf(t[0], vpx, fmaf(t[1], vpy, fmaf(t[2], vpz, t[3])));
                const int vv = vbase + nt * 16 + m;
                if (g < 3 && vv < V_)
                    out[((size_t)b * V_ + vv) * 3 + g] = o;
            }
        }
        wsync();   // h=0 reads drained before h=1 overwrites vp
    }
}

// ---------------------------------------------------------------------------
extern "C" void kernel_launch(void* const* d_in, const int* in_sizes, int n_in,
                              void* d_out, int out_size, void* d_ws, size_t ws_size,
                              hipStream_t stream)
{
    const float* betas         = (const float*)d_in[0];
    const float* body_pose     = (const float*)d_in[1];
    const float* global_orient = (const float*)d_in[2];
    const float* transl        = (const float*)d_in[3];
    const float* v_template    = (const float*)d_in[4];
    const float* shapedirs     = (const float*)d_in[5];
    const float* posedirs      = (const float*)d_in[6];
    const float* J_regressor   = (const float*)d_in[7];
    const float* lbs_weights   = (const float*)d_in[8];

    float* out = (float*)d_out;
    float* ws  = (float*)d_ws;

    // ws layout: JS[720] JT[72] f32 | pf bf16 [512*224] | At bf16 [8192*64]
    //            | pdT bf16 [CPAD*224]
    float* JS = ws;
    float* JT = ws + 720;
    unsigned short* pfw = (unsigned short*)(ws + 792);
    unsigned short* Atw = pfw + (size_t)B_ * KPAD;
    unsigned short* pdT = Atw + (size_t)B_ * 16 * 64;

    const size_t needed_pre = 792u * 4 + (size_t)B_ * KPAD * 2
                            + (size_t)B_ * 16 * 64 * 2
                            + (size_t)CPAD * KPAD * 2;   // ~10.57 MB
    const bool pre = (ws_size >= needed_pre);

    float* joints = out + (size_t)B_ * V_ * 3;

    k_prep<<<NCVT + 72, 256, 0, stream>>>(posedirs, shapedirs, J_regressor,
                                          v_template, pdT, JS, JT, pre ? 1 : 0);
    k_pose<<<B_ / 4, 256, 0, stream>>>(betas, body_pose, global_orient, transl,
                                       JS, JT, Atw, pfw, joints);
    if (pre) {
        k_verts<true><<<864, 256, 0, stream>>>(v_template, posedirs, shapedirs,
                                               pdT, lbs_weights, pfw, Atw, out);
    } else {
        k_verts<false><<<864, 256, 0, stream>>>(v_template, posedirs, shapedirs,
                                                pdT, lbs_weights, pfw, Atw, out);
    }
}